// Round 8
// baseline (233.332 us; speedup 1.0000x reference)
//
#include <hip/hip_runtime.h>

#define N_NODES 50000
#define NB ((N_NODES + 255) / 256)   // 196 scan blocks

using half8 = __attribute__((ext_vector_type(8))) _Float16;
using half4 = __attribute__((ext_vector_type(4))) _Float16;
using f32x4 = __attribute__((ext_vector_type(4))) float;

// Workspace layout (4-byte units):
//   dinv   [0,       50000)    float
//   rowptr [50048,  100049)    int (50001)
//   desc   [100096, 100292)    uint (lookback descriptors, 196)
//   cnt    [100608, 150608)    int (in-degree histogram)
//   esrc   [150656, 950656)    int (src per CSR slot)
//   epos   [950656, 1750656)   int (within-bucket position per edge)
//   W1t    [1750656, +8192)    fp16 [128c][128k] transposed+swizzled
//   W2t    [1758848, +4096)    fp16 [64c][128k]  transposed+swizzled
//   h1b    [1762944, +3200000) bf16 50000x128 (=h1*dinv); reused as h2b 50000x64
//   out1h  [4962944, +3200000) fp16 50000x128
//   z      [8162944, +1600000) fp16 50000x64 (decoder input)
// total = 9,762,944 floats = 39.1 MB

#define OFF_ROWPTR 50048
#define OFF_DESC   100096
#define OFF_CNT    100608
#define OFF_ESRC   150656
#define OFF_EPOS   950656
#define OFF_W1T    1750656
#define OFF_W2T    1758848
#define OFF_H1B    1762944
#define OFF_OUT1   4962944
#define OFF_Z      8162944

__device__ __forceinline__ ushort f2bf(float f) {
  uint u = __float_as_uint(f);
  u += 0x7fffu + ((u >> 16) & 1u);   // RNE
  return (ushort)(u >> 16);
}
__device__ __forceinline__ uint pack2(float a, float b) {
  return (uint)f2bf(a) | ((uint)f2bf(b) << 16);
}
__device__ __forceinline__ uint pack2h(float a, float b) {
  ushort ua = __builtin_bit_cast(ushort, (_Float16)a);
  ushort ub = __builtin_bit_cast(ushort, (_Float16)b);
  return (uint)ua | ((uint)ub << 16);
}
__device__ __forceinline__ float blo(uint u) { return __uint_as_float(u << 16); }
__device__ __forceinline__ float bhi(uint u) { return __uint_as_float(u & 0xffff0000u); }

// ---------------- fused: zero histogram + zero lookback desc + weight prep ---
__global__ __launch_bounds__(256) void k_zero_prep(int* __restrict__ cnt,
                                                   uint* __restrict__ desc,
                                                   const float* __restrict__ W1,
                                                   const float* __restrict__ W2,
                                                   _Float16* __restrict__ W1t,
                                                   _Float16* __restrict__ W2t) {
  int bid = blockIdx.x;
  if (bid < NB) {
    int i = bid * 256 + threadIdx.x;
    if (i < N_NODES) cnt[i] = 0;
    if (bid == 0 && threadIdx.x < NB) desc[threadIdx.x] = 0;  // state=0
    return;
  }
  int i = (bid - NB) * 256 + threadIdx.x;
  if (i < 16384) {
    int c = i >> 7, k = i & 127;
    W1t[c * 128 + (k ^ ((c & 7) << 3))] = (_Float16)W1[k * 128 + c];
  } else if (i < 24576) {
    int j = i - 16384;
    int c = j >> 7, k = j & 127;
    W2t[c * 128 + (k ^ ((c & 7) << 3))] = (_Float16)W2[k * 64 + c];
  }
}

__global__ __launch_bounds__(256) void k_hist(const int* __restrict__ dst, int E,
                                              int* __restrict__ cnt,
                                              int* __restrict__ epos) {
  int i = blockIdx.x * 256 + threadIdx.x;
  if (i < E) epos[i] = atomicAdd(&cnt[dst[i]], 1);
}

// single-kernel exclusive scan via decoupled lookback; also computes dinv.
// state word: (st<<30)|value; st: 0=empty, 1=aggregate, 2=inclusive prefix.
__global__ __launch_bounds__(256) void k_scanlb(const int* __restrict__ cnt,
                                                int* __restrict__ rowptr,
                                                float* __restrict__ dinv,
                                                uint* __restrict__ desc, int E) {
  __shared__ int tmp[256];
  __shared__ int s_prefix;
  const int b = blockIdx.x;
  const int i = b * 256 + threadIdx.x;
  int v = (i < N_NODES) ? cnt[i] : 0;
  tmp[threadIdx.x] = v;
  __syncthreads();
  for (int off = 1; off < 256; off <<= 1) {
    int t = (threadIdx.x >= off) ? tmp[threadIdx.x - off] : 0;
    __syncthreads();
    tmp[threadIdx.x] += t;
    __syncthreads();
  }
  int incl = tmp[threadIdx.x];
  int total = tmp[255];

  if (threadIdx.x == 0) {
    if (b == 0) {
      atomicExch(&desc[0], (2u << 30) | (uint)total);
      s_prefix = 0;
    } else {
      atomicExch(&desc[b], (1u << 30) | (uint)total);
      int run = 0;
      int j = b - 1;
      while (true) {
        uint w = atomicAdd(&desc[j], 0u);   // device-scope coherent read
        uint st = w >> 30;
        if (st == 0u) continue;             // not yet published: spin
        run += (int)(w & 0x3FFFFFFFu);
        if (st == 2u) break;                // inclusive prefix found
        --j;
      }
      atomicExch(&desc[b], (2u << 30) | (uint)(run + total));
      s_prefix = run;
    }
  }
  __syncthreads();
  int run = s_prefix;
  if (i < N_NODES) {
    rowptr[i] = run + incl - v;             // exclusive prefix
    dinv[i] = rsqrtf(1.0f + (float)v);
  }
  if (b == NB - 1 && threadIdx.x == 0) rowptr[N_NODES] = E;
}

__global__ __launch_bounds__(256) void k_fill(const int* __restrict__ src,
                                              const int* __restrict__ dst,
                                              const int* __restrict__ epos, int E,
                                              const int* __restrict__ rowptr,
                                              int* __restrict__ esrc) {
  int e = blockIdx.x * 256 + threadIdx.x;
  if (e < E) esrc[rowptr[dst[e]] + epos[e]] = src[e];
}

// ---------------- layer 1 GEMM (MFMA f16): h1b = bf16((x @ W1) * dinv) -------
__global__ __launch_bounds__(256) void k_gemm1(const float* __restrict__ x,
                                               const _Float16* __restrict__ W1t,
                                               const float* __restrict__ dinv,
                                               ushort* __restrict__ h1b) {
  __shared__ _Float16 Wl[128 * 128];   // 32 KB (pre-swizzled)
  __shared__ _Float16 xs[64 * 128];    // 16 KB (swizzled here)
  const int tid = threadIdx.x;
  const int lane = tid & 63;
  const int wv = tid >> 6;
  const int n0 = blockIdx.x * 64;

  for (int i = tid; i < 128 * 128 / 8; i += 256)
    *(float4*)&Wl[i * 8] = *(const float4*)&W1t[i * 8];
  for (int i = tid; i < 64 * 32; i += 256) {
    int nn = i >> 5, k4 = (i & 31) * 4;
    int gr = min(n0 + nn, N_NODES - 1);
    float4 v = *(const float4*)&x[(size_t)gr * 128 + k4];
    half4 hv;
    hv[0] = (_Float16)v.x; hv[1] = (_Float16)v.y;
    hv[2] = (_Float16)v.z; hv[3] = (_Float16)v.w;
    *(half4*)&xs[nn * 128 + (k4 ^ ((nn & 7) << 3))] = hv;
  }
  __syncthreads();

  f32x4 acc[8];
#pragma unroll
  for (int c = 0; c < 8; ++c) acc[c] = (f32x4){0.f, 0.f, 0.f, 0.f};

  const int m15 = lane & 15;
  const int kc = lane >> 4;
  const int xrow = wv * 16 + m15;

#pragma unroll
  for (int kt = 0; kt < 4; ++kt) {
    int e0 = kt * 32 + kc * 8;
    half8 bfrag = *(half8*)&xs[xrow * 128 + (e0 ^ ((xrow & 7) << 3))];
#pragma unroll
    for (int ct = 0; ct < 8; ++ct) {
      int wrow = ct * 16 + m15;
      half8 afrag = *(half8*)&Wl[wrow * 128 + (e0 ^ ((wrow & 7) << 3))];
      acc[ct] = __builtin_amdgcn_mfma_f32_16x16x32_f16(afrag, bfrag, acc[ct], 0, 0, 0);
    }
  }

  int n = n0 + wv * 16 + m15;
  if (n < N_NODES) {
    float dl = dinv[n];
#pragma unroll
    for (int ct = 0; ct < 8; ++ct) {
      int c = ct * 16 + kc * 4;
      uint2 p;
      p.x = pack2(acc[ct][0] * dl, acc[ct][1] * dl);
      p.y = pack2(acc[ct][2] * dl, acc[ct][3] * dl);
      *(uint2*)&h1b[(size_t)n * 128 + c] = p;
    }
  }
}

// out1h[n] = fp16(dinv[n]*(h1b[n] + sum_{s} h1b[s]) + b1)
__global__ __launch_bounds__(256) void k_pull1(const int* __restrict__ rowptr,
                                               const int* __restrict__ esrc,
                                               const float* __restrict__ dinv,
                                               const uint* __restrict__ h1b,
                                               const float* __restrict__ b1,
                                               uint* __restrict__ out1h) {
  int n = (blockIdx.x * 256 + threadIdx.x) >> 6;
  int lane = threadIdx.x & 63;
  if (n >= N_NODES) return;
  int b = rowptr[n], e = rowptr[n + 1];
  int deg = e - b;

  uint u = h1b[(size_t)n * 64 + lane];   // self-loop
  float a0 = blo(u), a1 = bhi(u);

  int sidx = (lane < deg) ? esrc[b + lane] : 0;
  int kmax = deg < 64 ? deg : 64;
  int k = 0;
  for (; k + 15 < kmax; k += 16) {
    uint uu[16];
#pragma unroll
    for (int q = 0; q < 16; ++q) {
      int s = __shfl(sidx, k + q, 64);
      uu[q] = h1b[(size_t)s * 64 + lane];
    }
#pragma unroll
    for (int q = 0; q < 16; ++q) { a0 += blo(uu[q]); a1 += bhi(uu[q]); }
  }
  for (; k + 7 < kmax; k += 8) {
    uint uu[8];
#pragma unroll
    for (int q = 0; q < 8; ++q) {
      int s = __shfl(sidx, k + q, 64);
      uu[q] = h1b[(size_t)s * 64 + lane];
    }
#pragma unroll
    for (int q = 0; q < 8; ++q) { a0 += blo(uu[q]); a1 += bhi(uu[q]); }
  }
  for (; k < kmax; ++k) {
    int s = __shfl(sidx, k, 64);
    uint uu = h1b[(size_t)s * 64 + lane];
    a0 += blo(uu);
    a1 += bhi(uu);
  }
  for (int j = b + 64; j < e; ++j) {
    uint uu = h1b[(size_t)esrc[j] * 64 + lane];
    a0 += blo(uu);
    a1 += bhi(uu);
  }

  float dd = dinv[n];
  float2 bb = ((const float2*)b1)[lane];
  out1h[(size_t)n * 64 + lane] = pack2h(fmaf(dd, a0, bb.x), fmaf(dd, a1, bb.y));
}

// ---------------- layer 2 GEMM (MFMA f16): h2b = bf16((relu(out1h)@W2)*dinv) -
__global__ __launch_bounds__(256) void k_gemm2(const _Float16* __restrict__ out1h,
                                               const _Float16* __restrict__ W2t,
                                               const float* __restrict__ dinv,
                                               ushort* __restrict__ h2b) {
  __shared__ _Float16 Wl[64 * 128];    // 16 KB
  __shared__ _Float16 xs[64 * 128];    // 16 KB
  const int tid = threadIdx.x;
  const int lane = tid & 63;
  const int wv = tid >> 6;
  const int n0 = blockIdx.x * 64;

  for (int i = tid; i < 64 * 128 / 8; i += 256)
    *(float4*)&Wl[i * 8] = *(const float4*)&W2t[i * 8];
  for (int i = tid; i < 64 * 16; i += 256) {
    int nn = i >> 4, k8 = (i & 15) * 8;
    int gr = min(n0 + nn, N_NODES - 1);
    half8 v = *(const half8*)&out1h[(size_t)gr * 128 + k8];
#pragma unroll
    for (int q = 0; q < 8; ++q) v[q] = v[q] > (_Float16)0.f ? v[q] : (_Float16)0.f;
    *(half8*)&xs[nn * 128 + (k8 ^ ((nn & 7) << 3))] = v;
  }
  __syncthreads();

  f32x4 acc[4];
#pragma unroll
  for (int c = 0; c < 4; ++c) acc[c] = (f32x4){0.f, 0.f, 0.f, 0.f};

  const int m15 = lane & 15;
  const int kc = lane >> 4;
  const int xrow = wv * 16 + m15;

#pragma unroll
  for (int kt = 0; kt < 4; ++kt) {
    int e0 = kt * 32 + kc * 8;
    half8 bfrag = *(half8*)&xs[xrow * 128 + (e0 ^ ((xrow & 7) << 3))];
#pragma unroll
    for (int ct = 0; ct < 4; ++ct) {
      int wrow = ct * 16 + m15;
      half8 afrag = *(half8*)&Wl[wrow * 128 + (e0 ^ ((wrow & 7) << 3))];
      acc[ct] = __builtin_amdgcn_mfma_f32_16x16x32_f16(afrag, bfrag, acc[ct], 0, 0, 0);
    }
  }

  int n = n0 + wv * 16 + m15;
  if (n < N_NODES) {
    float dl = dinv[n];
#pragma unroll
    for (int ct = 0; ct < 4; ++ct) {
      int c = ct * 16 + kc * 4;
      uint2 p;
      p.x = pack2(acc[ct][0] * dl, acc[ct][1] * dl);
      p.y = pack2(acc[ct][2] * dl, acc[ct][3] * dl);
      *(uint2*)&h2b[(size_t)n * 64 + c] = p;
    }
  }
}

// z[n] = fp16(dinv[n]*(h2b[n] + sum h2b[s]) + b2)
__global__ __launch_bounds__(256) void k_pull2(const int* __restrict__ rowptr,
                                               const int* __restrict__ esrc,
                                               const float* __restrict__ dinv,
                                               const ushort* __restrict__ h2b,
                                               const float* __restrict__ b2,
                                               _Float16* __restrict__ z) {
  int n = (blockIdx.x * 256 + threadIdx.x) >> 6;
  int lane = threadIdx.x & 63;
  if (n >= N_NODES) return;
  int b = rowptr[n], e = rowptr[n + 1];
  int deg = e - b;

  float a = __uint_as_float((uint)h2b[(size_t)n * 64 + lane] << 16);  // self

  int sidx = (lane < deg) ? esrc[b + lane] : 0;
  int kmax = deg < 64 ? deg : 64;
  int k = 0;
  for (; k + 15 < kmax; k += 16) {
    ushort vv[16];
#pragma unroll
    for (int q = 0; q < 16; ++q) {
      int s = __shfl(sidx, k + q, 64);
      vv[q] = h2b[(size_t)s * 64 + lane];
    }
#pragma unroll
    for (int q = 0; q < 16; ++q) a += __uint_as_float((uint)vv[q] << 16);
  }
  for (; k + 7 < kmax; k += 8) {
    ushort vv[8];
#pragma unroll
    for (int q = 0; q < 8; ++q) {
      int s = __shfl(sidx, k + q, 64);
      vv[q] = h2b[(size_t)s * 64 + lane];
    }
#pragma unroll
    for (int q = 0; q < 8; ++q) a += __uint_as_float((uint)vv[q] << 16);
  }
  for (; k < kmax; ++k) {
    int s = __shfl(sidx, k, 64);
    a += __uint_as_float((uint)h2b[(size_t)s * 64 + lane] << 16);
  }
  for (int j = b + 64; j < e; ++j)
    a += __uint_as_float((uint)h2b[(size_t)esrc[j] * 64 + lane] << 16);

  z[(size_t)n * 64 + lane] = (_Float16)fmaf(dinv[n], a, b2[lane]);
}

// logits[e] = dot(z[a],z[b]) over 64 dims -- 8 lanes/edge, half8/lane
__global__ __launch_bounds__(256) void k_decode(const int* __restrict__ ia,
                                                const int* __restrict__ ib,
                                                const _Float16* __restrict__ z,
                                                float* __restrict__ out, int M) {
  const int sub = threadIdx.x & 7;
  int e = (blockIdx.x * 256 + threadIdx.x) >> 3;
  if (e >= M) return;
  int a = ia[e], b = ib[e];
  half8 va = ((const half8*)z)[(size_t)a * 8 + sub];
  half8 vb = ((const half8*)z)[(size_t)b * 8 + sub];
  float v = 0.f;
#pragma unroll
  for (int i = 0; i < 8; ++i) v += (float)va[i] * (float)vb[i];
  v += __shfl_xor(v, 4, 64);
  v += __shfl_xor(v, 2, 64);
  v += __shfl_xor(v, 1, 64);
  if (sub == 0) out[e] = v;
}

extern "C" void kernel_launch(void* const* d_in, const int* in_sizes, int n_in,
                              void* d_out, int out_size, void* d_ws, size_t ws_size,
                              hipStream_t stream) {
  const float* x   = (const float*)d_in[0];
  const int*   ei  = (const int*)d_in[1];
  const int*   eli = (const int*)d_in[2];
  const float* W1  = (const float*)d_in[3];
  const float* b1  = (const float*)d_in[4];
  const float* W2  = (const float*)d_in[5];
  const float* b2  = (const float*)d_in[6];
  float* outp = (float*)d_out;

  const int E = in_sizes[1] / 2;   // 800000
  const int M = in_sizes[2] / 2;   // 200000
  const int* src = ei;
  const int* dst = ei + E;
  const int* la  = eli;
  const int* lb  = eli + M;

  float* ws      = (float*)d_ws;
  float* dinv    = ws;
  int*   rowptr  = (int*)(ws + OFF_ROWPTR);
  uint*  desc    = (uint*)(ws + OFF_DESC);
  int*   cnt     = (int*)(ws + OFF_CNT);
  int*   esrc    = (int*)(ws + OFF_ESRC);
  int*   epos    = (int*)(ws + OFF_EPOS);
  _Float16* W1t  = (_Float16*)(ws + OFF_W1T);
  _Float16* W2t  = (_Float16*)(ws + OFF_W2T);
  ushort* h1b    = (ushort*)(ws + OFF_H1B);
  ushort* h2b    = (ushort*)(ws + OFF_H1B);   // reuse (h1b dead after pull1)
  _Float16* out1h = (_Float16*)(ws + OFF_OUT1);
  _Float16* z    = (_Float16*)(ws + OFF_Z);

  // CSR build + degree norm + weight prep
  k_zero_prep<<<NB + 96, 256, 0, stream>>>(cnt, desc, W1, W2, W1t, W2t);
  k_hist  <<<(E + 255) / 256, 256, 0, stream>>>(dst, E, cnt, epos);
  k_scanlb<<<NB, 256, 0, stream>>>(cnt, rowptr, dinv, desc, E);
  k_fill  <<<(E + 255) / 256, 256, 0, stream>>>(src, dst, epos, E, rowptr, esrc);

  // layer 1
  k_gemm1<<<(N_NODES + 63) / 64, 256, 0, stream>>>(x, W1t, dinv, h1b);
  k_pull1<<<12500, 256, 0, stream>>>(rowptr, esrc, dinv, (const uint*)h1b, b1,
                                     (uint*)out1h);

  // layer 2
  k_gemm2<<<(N_NODES + 63) / 64, 256, 0, stream>>>(out1h, W2t, dinv, h2b);
  k_pull2<<<12500, 256, 0, stream>>>(rowptr, esrc, dinv, h2b, b2, z);

  // decode
  k_decode<<<6250, 256, 0, stream>>>(la, lb, z, outp, M);
}

// Round 9
// 227.389 us; speedup vs baseline: 1.0261x; 1.0261x over previous
//
#include <hip/hip_runtime.h>

#define N_NODES 50000
#define NB ((N_NODES + 255) / 256)   // 196 scan blocks

using half8 = __attribute__((ext_vector_type(8))) _Float16;
using half4 = __attribute__((ext_vector_type(4))) _Float16;
using f32x4 = __attribute__((ext_vector_type(4))) float;

// Workspace layout (4-byte units):
//   dinv   [0,       50000)    float
//   rowptr [50048,  100049)    int (50001)
//   desc   [100096, 100292)    uint (lookback descriptors, 196)
//   cnt    [100608, 150608)    int (in-degree histogram)
//   esrc   [150656, 950656)    int (src per CSR slot)
//   epos   [950656, 1750656)   int (within-bucket position per edge)
//   W1t    [1750656, +8192)    fp16 [128c][128k] transposed+swizzled
//   W2t    [1758848, +4096)    fp16 [64c][128k]  transposed+swizzled
//   h1b    [1762944, +3200000) bf16 50000x128 (=h1*dinv); reused as h2b 50000x64
//   out1h  [4962944, +3200000) fp16 50000x128
//   z      [8162944, +1600000) fp16 50000x64 (decoder input)
// total = 9,762,944 floats = 39.1 MB

#define OFF_ROWPTR 50048
#define OFF_DESC   100096
#define OFF_CNT    100608
#define OFF_ESRC   150656
#define OFF_EPOS   950656
#define OFF_W1T    1750656
#define OFF_W2T    1758848
#define OFF_H1B    1762944
#define OFF_OUT1   4962944
#define OFF_Z      8162944

__device__ __forceinline__ ushort f2bf(float f) {
  uint u = __float_as_uint(f);
  u += 0x7fffu + ((u >> 16) & 1u);   // RNE
  return (ushort)(u >> 16);
}
__device__ __forceinline__ uint pack2(float a, float b) {
  return (uint)f2bf(a) | ((uint)f2bf(b) << 16);
}
__device__ __forceinline__ uint pack2h(float a, float b) {
  ushort ua = __builtin_bit_cast(ushort, (_Float16)a);
  ushort ub = __builtin_bit_cast(ushort, (_Float16)b);
  return (uint)ua | ((uint)ub << 16);
}
__device__ __forceinline__ float blo(uint u) { return __uint_as_float(u << 16); }
__device__ __forceinline__ float bhi(uint u) { return __uint_as_float(u & 0xffff0000u); }

// ---------------- fused: zero histogram + zero lookback desc + weight prep ---
__global__ __launch_bounds__(256) void k_zero_prep(int* __restrict__ cnt,
                                                   uint* __restrict__ desc,
                                                   const float* __restrict__ W1,
                                                   const float* __restrict__ W2,
                                                   _Float16* __restrict__ W1t,
                                                   _Float16* __restrict__ W2t) {
  int bid = blockIdx.x;
  if (bid < NB) {
    int i = bid * 256 + threadIdx.x;
    if (i < N_NODES) cnt[i] = 0;
    if (bid == 0 && threadIdx.x < NB) desc[threadIdx.x] = 0;  // state=0
    return;
  }
  int i = (bid - NB) * 256 + threadIdx.x;
  if (i < 16384) {
    int c = i >> 7, k = i & 127;
    W1t[c * 128 + (k ^ ((c & 7) << 3))] = (_Float16)W1[k * 128 + c];
  } else if (i < 24576) {
    int j = i - 16384;
    int c = j >> 7, k = j & 127;
    W2t[c * 128 + (k ^ ((c & 7) << 3))] = (_Float16)W2[k * 64 + c];
  }
}

__global__ __launch_bounds__(256) void k_hist(const int* __restrict__ dst, int E,
                                              int* __restrict__ cnt,
                                              int* __restrict__ epos) {
  int i = blockIdx.x * 256 + threadIdx.x;
  if (i < E) epos[i] = atomicAdd(&cnt[dst[i]], 1);
}

// single-kernel exclusive scan, WAVE-PARALLEL decoupled lookback; computes dinv.
// desc word: (st<<30)|value; st: 0=empty, 1=aggregate, 2=inclusive prefix.
__global__ __launch_bounds__(256) void k_scanlb(const int* __restrict__ cnt,
                                                int* __restrict__ rowptr,
                                                float* __restrict__ dinv,
                                                uint* __restrict__ desc, int E) {
  __shared__ int tmp[256];
  __shared__ int s_prefix;
  const int b = blockIdx.x;
  const int i = b * 256 + threadIdx.x;
  int v = (i < N_NODES) ? cnt[i] : 0;
  tmp[threadIdx.x] = v;
  __syncthreads();
  for (int off = 1; off < 256; off <<= 1) {
    int t = (threadIdx.x >= off) ? tmp[threadIdx.x - off] : 0;
    __syncthreads();
    tmp[threadIdx.x] += t;
    __syncthreads();
  }
  int incl = tmp[threadIdx.x];
  int total = tmp[255];

  if (threadIdx.x == 0) {
    uint w0 = (b == 0) ? ((2u << 30) | (uint)total) : ((1u << 30) | (uint)total);
    atomicExch(&desc[b], w0);
    if (b == 0) s_prefix = 0;
  }
  if (b > 0 && threadIdx.x < 64) {
    const int lane = threadIdx.x;
    int run = 0;
    int j = b - 1;
    while (true) {
      int jj = j - lane;
      uint w = (jj >= 0) ? atomicAdd(&desc[jj], 0u) : (2u << 30);  // virtual prefix 0
      uint st = w >> 30;
      unsigned long long mz = __ballot(st == 0u);
      unsigned long long mp = __ballot(st == 2u);
      int fp = mp ? (__ffsll((long long)mp) - 1) : 64;  // nearest inclusive-prefix lane
      unsigned long long below = (fp >= 64) ? ~0ull : ((1ull << fp) - 1ull);
      if (mz & below) continue;                          // unpublished inside window: retry
      int contrib = (lane <= fp) ? (int)(w & 0x3FFFFFFFu) : 0;
      contrib += __shfl_down(contrib, 32, 64);
      contrib += __shfl_down(contrib, 16, 64);
      contrib += __shfl_down(contrib, 8, 64);
      contrib += __shfl_down(contrib, 4, 64);
      contrib += __shfl_down(contrib, 2, 64);
      contrib += __shfl_down(contrib, 1, 64);
      run += __shfl(contrib, 0, 64);
      if (fp < 64) break;                                // hit an inclusive prefix: done
      j -= 64;
    }
    if (lane == 0) {
      atomicExch(&desc[b], (2u << 30) | (uint)(run + total));
      s_prefix = run;
    }
  }
  __syncthreads();
  int run = s_prefix;
  if (i < N_NODES) {
    rowptr[i] = run + incl - v;             // exclusive prefix
    dinv[i] = rsqrtf(1.0f + (float)v);
  }
  if (b == NB - 1 && threadIdx.x == 0) rowptr[N_NODES] = E;
}

__global__ __launch_bounds__(256) void k_fill(const int* __restrict__ src,
                                              const int* __restrict__ dst,
                                              const int* __restrict__ epos, int E,
                                              const int* __restrict__ rowptr,
                                              int* __restrict__ esrc) {
  int e = blockIdx.x * 256 + threadIdx.x;
  if (e < E) esrc[rowptr[dst[e]] + epos[e]] = src[e];
}

// ---------------- layer 1 GEMM (MFMA f16): h1b = bf16((x @ W1) * dinv) -------
__global__ __launch_bounds__(256) void k_gemm1(const float* __restrict__ x,
                                               const _Float16* __restrict__ W1t,
                                               const float* __restrict__ dinv,
                                               ushort* __restrict__ h1b) {
  __shared__ _Float16 Wl[128 * 128];   // 32 KB (pre-swizzled)
  __shared__ _Float16 xs[64 * 128];    // 16 KB (swizzled here)
  const int tid = threadIdx.x;
  const int lane = tid & 63;
  const int wv = tid >> 6;
  const int n0 = blockIdx.x * 64;

  for (int i = tid; i < 128 * 128 / 8; i += 256)
    *(float4*)&Wl[i * 8] = *(const float4*)&W1t[i * 8];
  for (int i = tid; i < 64 * 32; i += 256) {
    int nn = i >> 5, k4 = (i & 31) * 4;
    int gr = min(n0 + nn, N_NODES - 1);
    float4 v = *(const float4*)&x[(size_t)gr * 128 + k4];
    half4 hv;
    hv[0] = (_Float16)v.x; hv[1] = (_Float16)v.y;
    hv[2] = (_Float16)v.z; hv[3] = (_Float16)v.w;
    *(half4*)&xs[nn * 128 + (k4 ^ ((nn & 7) << 3))] = hv;
  }
  __syncthreads();

  f32x4 acc[8];
#pragma unroll
  for (int c = 0; c < 8; ++c) acc[c] = (f32x4){0.f, 0.f, 0.f, 0.f};

  const int m15 = lane & 15;
  const int kc = lane >> 4;
  const int xrow = wv * 16 + m15;

#pragma unroll
  for (int kt = 0; kt < 4; ++kt) {
    int e0 = kt * 32 + kc * 8;
    half8 bfrag = *(half8*)&xs[xrow * 128 + (e0 ^ ((xrow & 7) << 3))];
#pragma unroll
    for (int ct = 0; ct < 8; ++ct) {
      int wrow = ct * 16 + m15;
      half8 afrag = *(half8*)&Wl[wrow * 128 + (e0 ^ ((wrow & 7) << 3))];
      acc[ct] = __builtin_amdgcn_mfma_f32_16x16x32_f16(afrag, bfrag, acc[ct], 0, 0, 0);
    }
  }

  int n = n0 + wv * 16 + m15;
  if (n < N_NODES) {
    float dl = dinv[n];
#pragma unroll
    for (int ct = 0; ct < 8; ++ct) {
      int c = ct * 16 + kc * 4;
      uint2 p;
      p.x = pack2(acc[ct][0] * dl, acc[ct][1] * dl);
      p.y = pack2(acc[ct][2] * dl, acc[ct][3] * dl);
      *(uint2*)&h1b[(size_t)n * 128 + c] = p;
    }
  }
}

// out1h[n] = fp16(dinv[n]*(h1b[n] + sum_{s} h1b[s]) + b1)
__global__ __launch_bounds__(256) void k_pull1(const int* __restrict__ rowptr,
                                               const int* __restrict__ esrc,
                                               const float* __restrict__ dinv,
                                               const uint* __restrict__ h1b,
                                               const float* __restrict__ b1,
                                               uint* __restrict__ out1h) {
  int n = (blockIdx.x * 256 + threadIdx.x) >> 6;
  int lane = threadIdx.x & 63;
  if (n >= N_NODES) return;
  int b = rowptr[n], e = rowptr[n + 1];
  int deg = e - b;

  uint u = h1b[(size_t)n * 64 + lane];   // self-loop
  float a0 = blo(u), a1 = bhi(u);

  int sidx = (lane < deg) ? esrc[b + lane] : 0;
  int kmax = deg < 64 ? deg : 64;
  int k = 0;
  for (; k + 15 < kmax; k += 16) {
    uint uu[16];
#pragma unroll
    for (int q = 0; q < 16; ++q) {
      int s = __shfl(sidx, k + q, 64);
      uu[q] = h1b[(size_t)s * 64 + lane];
    }
#pragma unroll
    for (int q = 0; q < 16; ++q) { a0 += blo(uu[q]); a1 += bhi(uu[q]); }
  }
  for (; k + 7 < kmax; k += 8) {
    uint uu[8];
#pragma unroll
    for (int q = 0; q < 8; ++q) {
      int s = __shfl(sidx, k + q, 64);
      uu[q] = h1b[(size_t)s * 64 + lane];
    }
#pragma unroll
    for (int q = 0; q < 8; ++q) { a0 += blo(uu[q]); a1 += bhi(uu[q]); }
  }
  for (; k < kmax; ++k) {
    int s = __shfl(sidx, k, 64);
    uint uu = h1b[(size_t)s * 64 + lane];
    a0 += blo(uu);
    a1 += bhi(uu);
  }
  for (int j = b + 64; j < e; ++j) {
    uint uu = h1b[(size_t)esrc[j] * 64 + lane];
    a0 += blo(uu);
    a1 += bhi(uu);
  }

  float dd = dinv[n];
  float2 bb = ((const float2*)b1)[lane];
  out1h[(size_t)n * 64 + lane] = pack2h(fmaf(dd, a0, bb.x), fmaf(dd, a1, bb.y));
}

// ---------------- layer 2 GEMM (MFMA f16): h2b = bf16((relu(out1h)@W2)*dinv) -
__global__ __launch_bounds__(256) void k_gemm2(const _Float16* __restrict__ out1h,
                                               const _Float16* __restrict__ W2t,
                                               const float* __restrict__ dinv,
                                               ushort* __restrict__ h2b) {
  __shared__ _Float16 Wl[64 * 128];    // 16 KB
  __shared__ _Float16 xs[64 * 128];    // 16 KB
  const int tid = threadIdx.x;
  const int lane = tid & 63;
  const int wv = tid >> 6;
  const int n0 = blockIdx.x * 64;

  for (int i = tid; i < 64 * 128 / 8; i += 256)
    *(float4*)&Wl[i * 8] = *(const float4*)&W2t[i * 8];
  for (int i = tid; i < 64 * 16; i += 256) {
    int nn = i >> 4, k8 = (i & 15) * 8;
    int gr = min(n0 + nn, N_NODES - 1);
    half8 v = *(const half8*)&out1h[(size_t)gr * 128 + k8];
#pragma unroll
    for (int q = 0; q < 8; ++q) v[q] = v[q] > (_Float16)0.f ? v[q] : (_Float16)0.f;
    *(half8*)&xs[nn * 128 + (k8 ^ ((nn & 7) << 3))] = v;
  }
  __syncthreads();

  f32x4 acc[4];
#pragma unroll
  for (int c = 0; c < 4; ++c) acc[c] = (f32x4){0.f, 0.f, 0.f, 0.f};

  const int m15 = lane & 15;
  const int kc = lane >> 4;
  const int xrow = wv * 16 + m15;

#pragma unroll
  for (int kt = 0; kt < 4; ++kt) {
    int e0 = kt * 32 + kc * 8;
    half8 bfrag = *(half8*)&xs[xrow * 128 + (e0 ^ ((xrow & 7) << 3))];
#pragma unroll
    for (int ct = 0; ct < 4; ++ct) {
      int wrow = ct * 16 + m15;
      half8 afrag = *(half8*)&Wl[wrow * 128 + (e0 ^ ((wrow & 7) << 3))];
      acc[ct] = __builtin_amdgcn_mfma_f32_16x16x32_f16(afrag, bfrag, acc[ct], 0, 0, 0);
    }
  }

  int n = n0 + wv * 16 + m15;
  if (n < N_NODES) {
    float dl = dinv[n];
#pragma unroll
    for (int ct = 0; ct < 4; ++ct) {
      int c = ct * 16 + kc * 4;
      uint2 p;
      p.x = pack2(acc[ct][0] * dl, acc[ct][1] * dl);
      p.y = pack2(acc[ct][2] * dl, acc[ct][3] * dl);
      *(uint2*)&h2b[(size_t)n * 64 + c] = p;
    }
  }
}

// z[n] = fp16(dinv[n]*(h2b[n] + sum h2b[s]) + b2)
__global__ __launch_bounds__(256) void k_pull2(const int* __restrict__ rowptr,
                                               const int* __restrict__ esrc,
                                               const float* __restrict__ dinv,
                                               const ushort* __restrict__ h2b,
                                               const float* __restrict__ b2,
                                               _Float16* __restrict__ z) {
  int n = (blockIdx.x * 256 + threadIdx.x) >> 6;
  int lane = threadIdx.x & 63;
  if (n >= N_NODES) return;
  int b = rowptr[n], e = rowptr[n + 1];
  int deg = e - b;

  float a = __uint_as_float((uint)h2b[(size_t)n * 64 + lane] << 16);  // self

  int sidx = (lane < deg) ? esrc[b + lane] : 0;
  int kmax = deg < 64 ? deg : 64;
  int k = 0;
  for (; k + 15 < kmax; k += 16) {
    ushort vv[16];
#pragma unroll
    for (int q = 0; q < 16; ++q) {
      int s = __shfl(sidx, k + q, 64);
      vv[q] = h2b[(size_t)s * 64 + lane];
    }
#pragma unroll
    for (int q = 0; q < 16; ++q) a += __uint_as_float((uint)vv[q] << 16);
  }
  for (; k + 7 < kmax; k += 8) {
    ushort vv[8];
#pragma unroll
    for (int q = 0; q < 8; ++q) {
      int s = __shfl(sidx, k + q, 64);
      vv[q] = h2b[(size_t)s * 64 + lane];
    }
#pragma unroll
    for (int q = 0; q < 8; ++q) a += __uint_as_float((uint)vv[q] << 16);
  }
  for (; k < kmax; ++k) {
    int s = __shfl(sidx, k, 64);
    a += __uint_as_float((uint)h2b[(size_t)s * 64 + lane] << 16);
  }
  for (int j = b + 64; j < e; ++j)
    a += __uint_as_float((uint)h2b[(size_t)esrc[j] * 64 + lane] << 16);

  z[(size_t)n * 64 + lane] = (_Float16)fmaf(dinv[n], a, b2[lane]);
}

// logits[e] = dot(z[a],z[b]) over 64 dims -- 8 lanes/edge, half8/lane
__global__ __launch_bounds__(256) void k_decode(const int* __restrict__ ia,
                                                const int* __restrict__ ib,
                                                const _Float16* __restrict__ z,
                                                float* __restrict__ out, int M) {
  const int sub = threadIdx.x & 7;
  int e = (blockIdx.x * 256 + threadIdx.x) >> 3;
  if (e >= M) return;
  int a = ia[e], b = ib[e];
  half8 va = ((const half8*)z)[(size_t)a * 8 + sub];
  half8 vb = ((const half8*)z)[(size_t)b * 8 + sub];
  float v = 0.f;
#pragma unroll
  for (int i = 0; i < 8; ++i) v += (float)va[i] * (float)vb[i];
  v += __shfl_xor(v, 4, 64);
  v += __shfl_xor(v, 2, 64);
  v += __shfl_xor(v, 1, 64);
  if (sub == 0) out[e] = v;
}

extern "C" void kernel_launch(void* const* d_in, const int* in_sizes, int n_in,
                              void* d_out, int out_size, void* d_ws, size_t ws_size,
                              hipStream_t stream) {
  const float* x   = (const float*)d_in[0];
  const int*   ei  = (const int*)d_in[1];
  const int*   eli = (const int*)d_in[2];
  const float* W1  = (const float*)d_in[3];
  const float* b1  = (const float*)d_in[4];
  const float* W2  = (const float*)d_in[5];
  const float* b2  = (const float*)d_in[6];
  float* outp = (float*)d_out;

  const int E = in_sizes[1] / 2;   // 800000
  const int M = in_sizes[2] / 2;   // 200000
  const int* src = ei;
  const int* dst = ei + E;
  const int* la  = eli;
  const int* lb  = eli + M;

  float* ws      = (float*)d_ws;
  float* dinv    = ws;
  int*   rowptr  = (int*)(ws + OFF_ROWPTR);
  uint*  desc    = (uint*)(ws + OFF_DESC);
  int*   cnt     = (int*)(ws + OFF_CNT);
  int*   esrc    = (int*)(ws + OFF_ESRC);
  int*   epos    = (int*)(ws + OFF_EPOS);
  _Float16* W1t  = (_Float16*)(ws + OFF_W1T);
  _Float16* W2t  = (_Float16*)(ws + OFF_W2T);
  ushort* h1b    = (ushort*)(ws + OFF_H1B);
  ushort* h2b    = (ushort*)(ws + OFF_H1B);   // reuse (h1b dead after pull1)
  _Float16* out1h = (_Float16*)(ws + OFF_OUT1);
  _Float16* z    = (_Float16*)(ws + OFF_Z);

  // CSR build + degree norm + weight prep
  k_zero_prep<<<NB + 96, 256, 0, stream>>>(cnt, desc, W1, W2, W1t, W2t);
  k_hist  <<<(E + 255) / 256, 256, 0, stream>>>(dst, E, cnt, epos);
  k_scanlb<<<NB, 256, 0, stream>>>(cnt, rowptr, dinv, desc, E);
  k_fill  <<<(E + 255) / 256, 256, 0, stream>>>(src, dst, epos, E, rowptr, esrc);

  // layer 1
  k_gemm1<<<(N_NODES + 63) / 64, 256, 0, stream>>>(x, W1t, dinv, h1b);
  k_pull1<<<12500, 256, 0, stream>>>(rowptr, esrc, dinv, (const uint*)h1b, b1,
                                     (uint*)out1h);

  // layer 2
  k_gemm2<<<(N_NODES + 63) / 64, 256, 0, stream>>>(out1h, W2t, dinv, h2b);
  k_pull2<<<12500, 256, 0, stream>>>(rowptr, esrc, dinv, h2b, b2, z);

  // decode
  k_decode<<<6250, 256, 0, stream>>>(la, lb, z, outp, M);
}

// Round 10
// 227.132 us; speedup vs baseline: 1.0273x; 1.0011x over previous
//
#include <hip/hip_runtime.h>

#define N_NODES 50000
#define NB ((N_NODES + 255) / 256)   // 196 scan blocks
#define FILLB 3125                    // (E + 255)/256 for E=800000

using half8 = __attribute__((ext_vector_type(8))) _Float16;
using half4 = __attribute__((ext_vector_type(4))) _Float16;
using f32x4 = __attribute__((ext_vector_type(4))) float;

// Workspace layout (4-byte units):
//   dinv   [0,       50000)    float
//   rowptr [50048,  100049)    int (50001)
//   desc   [100096, 100292)    uint (lookback descriptors, 196)
//   cnt    [100608, 150608)    int (in-degree histogram)
//   esrc   [150656, 950656)    int (src per CSR slot)
//   epos   [950656, 1750656)   uint packed (pos<<17 | dst) per edge
//   W1t    [1750656, +8192)    fp16 [128c][128k] transposed+swizzled
//   W2t    [1758848, +4096)    fp16 [64c][128k]  transposed+swizzled
//   h1b    [1762944, +3200000) bf16 50000x128 (=h1*dinv); reused as h2b 50000x64
//   out1h  [4962944, +3200000) fp16 50000x128
//   z      [8162944, +1600000) fp16 50000x64 (decoder input)

#define OFF_ROWPTR 50048
#define OFF_DESC   100096
#define OFF_CNT    100608
#define OFF_ESRC   150656
#define OFF_EPOS   950656
#define OFF_W1T    1750656
#define OFF_W2T    1758848
#define OFF_H1B    1762944
#define OFF_OUT1   4962944
#define OFF_Z      8162944

__device__ __forceinline__ ushort f2bf(float f) {
  uint u = __float_as_uint(f);
  u += 0x7fffu + ((u >> 16) & 1u);   // RNE
  return (ushort)(u >> 16);
}
__device__ __forceinline__ uint pack2(float a, float b) {
  return (uint)f2bf(a) | ((uint)f2bf(b) << 16);
}
__device__ __forceinline__ uint pack2h(float a, float b) {
  ushort ua = __builtin_bit_cast(ushort, (_Float16)a);
  ushort ub = __builtin_bit_cast(ushort, (_Float16)b);
  return (uint)ua | ((uint)ub << 16);
}
__device__ __forceinline__ float blo(uint u) { return __uint_as_float(u << 16); }
__device__ __forceinline__ float bhi(uint u) { return __uint_as_float(u & 0xffff0000u); }

// ---------------- fused: zero histogram + zero lookback desc + weight prep ---
__global__ __launch_bounds__(256) void k_zero_prep(int* __restrict__ cnt,
                                                   uint* __restrict__ desc,
                                                   const float* __restrict__ W1,
                                                   const float* __restrict__ W2,
                                                   _Float16* __restrict__ W1t,
                                                   _Float16* __restrict__ W2t) {
  int bid = blockIdx.x;
  if (bid < NB) {
    int i = bid * 256 + threadIdx.x;
    if (i < N_NODES) cnt[i] = 0;
    if (bid == 0 && threadIdx.x < NB) desc[threadIdx.x] = 0;  // state=0
    return;
  }
  int i = (bid - NB) * 256 + threadIdx.x;
  if (i < 16384) {
    int c = i >> 7, k = i & 127;
    W1t[c * 128 + (k ^ ((c & 7) << 3))] = (_Float16)W1[k * 128 + c];
  } else if (i < 24576) {
    int j = i - 16384;
    int c = j >> 7, k = j & 127;
    W2t[c * 128 + (k ^ ((c & 7) << 3))] = (_Float16)W2[k * 64 + c];
  }
}

// histogram; epos stores (pos<<17)|dst packed (max deg << 32768, dst < 131072)
__global__ __launch_bounds__(256) void k_hist(const int* __restrict__ dst, int E,
                                              int* __restrict__ cnt,
                                              uint* __restrict__ epos) {
  int i = blockIdx.x * 256 + threadIdx.x;
  if (i < E) {
    int d = dst[i];
    int pos = atomicAdd(&cnt[d], 1);
    epos[i] = ((uint)pos << 17) | (uint)d;
  }
}

// single-kernel exclusive scan, WAVE-PARALLEL decoupled lookback; computes dinv.
__global__ __launch_bounds__(256) void k_scanlb(const int* __restrict__ cnt,
                                                int* __restrict__ rowptr,
                                                float* __restrict__ dinv,
                                                uint* __restrict__ desc, int E) {
  __shared__ int tmp[256];
  __shared__ int s_prefix;
  const int b = blockIdx.x;
  const int i = b * 256 + threadIdx.x;
  int v = (i < N_NODES) ? cnt[i] : 0;
  tmp[threadIdx.x] = v;
  __syncthreads();
  for (int off = 1; off < 256; off <<= 1) {
    int t = (threadIdx.x >= off) ? tmp[threadIdx.x - off] : 0;
    __syncthreads();
    tmp[threadIdx.x] += t;
    __syncthreads();
  }
  int incl = tmp[threadIdx.x];
  int total = tmp[255];

  if (threadIdx.x == 0) {
    uint w0 = (b == 0) ? ((2u << 30) | (uint)total) : ((1u << 30) | (uint)total);
    atomicExch(&desc[b], w0);
    if (b == 0) s_prefix = 0;
  }
  if (b > 0 && threadIdx.x < 64) {
    const int lane = threadIdx.x;
    int run = 0;
    int j = b - 1;
    while (true) {
      int jj = j - lane;
      uint w = (jj >= 0) ? atomicAdd(&desc[jj], 0u) : (2u << 30);  // virtual prefix 0
      uint st = w >> 30;
      unsigned long long mz = __ballot(st == 0u);
      unsigned long long mp = __ballot(st == 2u);
      int fp = mp ? (__ffsll((long long)mp) - 1) : 64;
      unsigned long long below = (fp >= 64) ? ~0ull : ((1ull << fp) - 1ull);
      if (mz & below) continue;
      int contrib = (lane <= fp) ? (int)(w & 0x3FFFFFFFu) : 0;
      contrib += __shfl_down(contrib, 32, 64);
      contrib += __shfl_down(contrib, 16, 64);
      contrib += __shfl_down(contrib, 8, 64);
      contrib += __shfl_down(contrib, 4, 64);
      contrib += __shfl_down(contrib, 2, 64);
      contrib += __shfl_down(contrib, 1, 64);
      run += __shfl(contrib, 0, 64);
      if (fp < 64) break;
      j -= 64;
    }
    if (lane == 0) {
      atomicExch(&desc[b], (2u << 30) | (uint)(run + total));
      s_prefix = run;
    }
  }
  __syncthreads();
  int run = s_prefix;
  if (i < N_NODES) {
    rowptr[i] = run + incl - v;
    dinv[i] = rsqrtf(1.0f + (float)v);
  }
  if (b == NB - 1 && threadIdx.x == 0) rowptr[N_NODES] = E;
}

// ---------------- fused: CSR fill (blocks 0..FILLB-1) + layer-1 GEMM --------
// gemm1 reads W fragments directly from global (pre-swizzled, L1/L2-resident);
// only the x tile is staged in LDS, keeping the fused kernel at 16 KB LDS so
// fill blocks keep full occupancy.
__global__ __launch_bounds__(256) void k_fill_gemm1(const int* __restrict__ src,
                                                    const uint* __restrict__ epos,
                                                    int E,
                                                    const int* __restrict__ rowptr,
                                                    int* __restrict__ esrc,
                                                    const float* __restrict__ x,
                                                    const _Float16* __restrict__ W1t,
                                                    const float* __restrict__ dinv,
                                                    ushort* __restrict__ h1b) {
  __shared__ _Float16 xs[64 * 128];    // 16 KB
  if (blockIdx.x < FILLB) {
    int e = blockIdx.x * 256 + threadIdx.x;
    if (e < E) {
      uint w = epos[e];
      int d = (int)(w & 0x1FFFFu);
      esrc[rowptr[d] + (int)(w >> 17)] = src[e];
    }
    return;
  }
  const int bid = blockIdx.x - FILLB;
  const int tid = threadIdx.x;
  const int lane = tid & 63;
  const int wv = tid >> 6;
  const int n0 = bid * 64;

  for (int i = tid; i < 64 * 32; i += 256) {
    int nn = i >> 5, k4 = (i & 31) * 4;
    int gr = min(n0 + nn, N_NODES - 1);
    float4 v = *(const float4*)&x[(size_t)gr * 128 + k4];
    half4 hv;
    hv[0] = (_Float16)v.x; hv[1] = (_Float16)v.y;
    hv[2] = (_Float16)v.z; hv[3] = (_Float16)v.w;
    *(half4*)&xs[nn * 128 + (k4 ^ ((nn & 7) << 3))] = hv;
  }
  __syncthreads();

  f32x4 acc[8];
#pragma unroll
  for (int c = 0; c < 8; ++c) acc[c] = (f32x4){0.f, 0.f, 0.f, 0.f};

  const int m15 = lane & 15;
  const int kc = lane >> 4;
  const int xrow = wv * 16 + m15;
  const int wsw = (m15 & 7) << 3;      // swizzle offset (uniform across ct)

#pragma unroll
  for (int kt = 0; kt < 4; ++kt) {
    int e0 = kt * 32 + kc * 8;
    half8 bfrag = *(half8*)&xs[xrow * 128 + (e0 ^ ((xrow & 7) << 3))];
#pragma unroll
    for (int ct = 0; ct < 8; ++ct) {
      int wrow = ct * 16 + m15;
      half8 afrag = *(const half8*)&W1t[wrow * 128 + (e0 ^ wsw)];
      acc[ct] = __builtin_amdgcn_mfma_f32_16x16x32_f16(afrag, bfrag, acc[ct], 0, 0, 0);
    }
  }

  int n = n0 + wv * 16 + m15;
  if (n < N_NODES) {
    float dl = dinv[n];
#pragma unroll
    for (int ct = 0; ct < 8; ++ct) {
      int c = ct * 16 + kc * 4;
      uint2 p;
      p.x = pack2(acc[ct][0] * dl, acc[ct][1] * dl);
      p.y = pack2(acc[ct][2] * dl, acc[ct][3] * dl);
      *(uint2*)&h1b[(size_t)n * 128 + c] = p;
    }
  }
}

// out1h[n] = fp16(dinv[n]*(h1b[n] + sum_{s} h1b[s]) + b1)
__global__ __launch_bounds__(256) void k_pull1(const int* __restrict__ rowptr,
                                               const int* __restrict__ esrc,
                                               const float* __restrict__ dinv,
                                               const uint* __restrict__ h1b,
                                               const float* __restrict__ b1,
                                               uint* __restrict__ out1h) {
  int n = (blockIdx.x * 256 + threadIdx.x) >> 6;
  int lane = threadIdx.x & 63;
  if (n >= N_NODES) return;
  int b = rowptr[n], e = rowptr[n + 1];
  int deg = e - b;

  uint u = h1b[(size_t)n * 64 + lane];   // self-loop
  float a0 = blo(u), a1 = bhi(u);

  int sidx = (lane < deg) ? esrc[b + lane] : 0;
  int kmax = deg < 64 ? deg : 64;
  int k = 0;
  for (; k + 15 < kmax; k += 16) {
    uint uu[16];
#pragma unroll
    for (int q = 0; q < 16; ++q) {
      int s = __shfl(sidx, k + q, 64);
      uu[q] = h1b[(size_t)s * 64 + lane];
    }
#pragma unroll
    for (int q = 0; q < 16; ++q) { a0 += blo(uu[q]); a1 += bhi(uu[q]); }
  }
  for (; k + 7 < kmax; k += 8) {
    uint uu[8];
#pragma unroll
    for (int q = 0; q < 8; ++q) {
      int s = __shfl(sidx, k + q, 64);
      uu[q] = h1b[(size_t)s * 64 + lane];
    }
#pragma unroll
    for (int q = 0; q < 8; ++q) { a0 += blo(uu[q]); a1 += bhi(uu[q]); }
  }
  for (; k < kmax; ++k) {
    int s = __shfl(sidx, k, 64);
    uint uu = h1b[(size_t)s * 64 + lane];
    a0 += blo(uu);
    a1 += bhi(uu);
  }
  for (int j = b + 64; j < e; ++j) {
    uint uu = h1b[(size_t)esrc[j] * 64 + lane];
    a0 += blo(uu);
    a1 += bhi(uu);
  }

  float dd = dinv[n];
  float2 bb = ((const float2*)b1)[lane];
  out1h[(size_t)n * 64 + lane] = pack2h(fmaf(dd, a0, bb.x), fmaf(dd, a1, bb.y));
}

// ---------------- layer 2 GEMM (MFMA f16): h2b = bf16((relu(out1h)@W2)*dinv) -
__global__ __launch_bounds__(256) void k_gemm2(const _Float16* __restrict__ out1h,
                                               const _Float16* __restrict__ W2t,
                                               const float* __restrict__ dinv,
                                               ushort* __restrict__ h2b) {
  __shared__ _Float16 Wl[64 * 128];    // 16 KB
  __shared__ _Float16 xs[64 * 128];    // 16 KB
  const int tid = threadIdx.x;
  const int lane = tid & 63;
  const int wv = tid >> 6;
  const int n0 = blockIdx.x * 64;

  for (int i = tid; i < 64 * 128 / 8; i += 256)
    *(float4*)&Wl[i * 8] = *(const float4*)&W2t[i * 8];
  for (int i = tid; i < 64 * 16; i += 256) {
    int nn = i >> 4, k8 = (i & 15) * 8;
    int gr = min(n0 + nn, N_NODES - 1);
    half8 v = *(const half8*)&out1h[(size_t)gr * 128 + k8];
#pragma unroll
    for (int q = 0; q < 8; ++q) v[q] = v[q] > (_Float16)0.f ? v[q] : (_Float16)0.f;
    *(half8*)&xs[nn * 128 + (k8 ^ ((nn & 7) << 3))] = v;
  }
  __syncthreads();

  f32x4 acc[4];
#pragma unroll
  for (int c = 0; c < 4; ++c) acc[c] = (f32x4){0.f, 0.f, 0.f, 0.f};

  const int m15 = lane & 15;
  const int kc = lane >> 4;
  const int xrow = wv * 16 + m15;

#pragma unroll
  for (int kt = 0; kt < 4; ++kt) {
    int e0 = kt * 32 + kc * 8;
    half8 bfrag = *(half8*)&xs[xrow * 128 + (e0 ^ ((xrow & 7) << 3))];
#pragma unroll
    for (int ct = 0; ct < 4; ++ct) {
      int wrow = ct * 16 + m15;
      half8 afrag = *(half8*)&Wl[wrow * 128 + (e0 ^ ((wrow & 7) << 3))];
      acc[ct] = __builtin_amdgcn_mfma_f32_16x16x32_f16(afrag, bfrag, acc[ct], 0, 0, 0);
    }
  }

  int n = n0 + wv * 16 + m15;
  if (n < N_NODES) {
    float dl = dinv[n];
#pragma unroll
    for (int ct = 0; ct < 4; ++ct) {
      int c = ct * 16 + kc * 4;
      uint2 p;
      p.x = pack2(acc[ct][0] * dl, acc[ct][1] * dl);
      p.y = pack2(acc[ct][2] * dl, acc[ct][3] * dl);
      *(uint2*)&h2b[(size_t)n * 64 + c] = p;
    }
  }
}

// z[n] = fp16(dinv[n]*(h2b[n] + sum h2b[s]) + b2)
__global__ __launch_bounds__(256) void k_pull2(const int* __restrict__ rowptr,
                                               const int* __restrict__ esrc,
                                               const float* __restrict__ dinv,
                                               const ushort* __restrict__ h2b,
                                               const float* __restrict__ b2,
                                               _Float16* __restrict__ z) {
  int n = (blockIdx.x * 256 + threadIdx.x) >> 6;
  int lane = threadIdx.x & 63;
  if (n >= N_NODES) return;
  int b = rowptr[n], e = rowptr[n + 1];
  int deg = e - b;

  float a = __uint_as_float((uint)h2b[(size_t)n * 64 + lane] << 16);  // self

  int sidx = (lane < deg) ? esrc[b + lane] : 0;
  int kmax = deg < 64 ? deg : 64;
  int k = 0;
  for (; k + 15 < kmax; k += 16) {
    ushort vv[16];
#pragma unroll
    for (int q = 0; q < 16; ++q) {
      int s = __shfl(sidx, k + q, 64);
      vv[q] = h2b[(size_t)s * 64 + lane];
    }
#pragma unroll
    for (int q = 0; q < 16; ++q) a += __uint_as_float((uint)vv[q] << 16);
  }
  for (; k + 7 < kmax; k += 8) {
    ushort vv[8];
#pragma unroll
    for (int q = 0; q < 8; ++q) {
      int s = __shfl(sidx, k + q, 64);
      vv[q] = h2b[(size_t)s * 64 + lane];
    }
#pragma unroll
    for (int q = 0; q < 8; ++q) a += __uint_as_float((uint)vv[q] << 16);
  }
  for (; k < kmax; ++k) {
    int s = __shfl(sidx, k, 64);
    a += __uint_as_float((uint)h2b[(size_t)s * 64 + lane] << 16);
  }
  for (int j = b + 64; j < e; ++j)
    a += __uint_as_float((uint)h2b[(size_t)esrc[j] * 64 + lane] << 16);

  z[(size_t)n * 64 + lane] = (_Float16)fmaf(dinv[n], a, b2[lane]);
}

// logits[e] = dot(z[a],z[b]) -- 8 lanes/edge; wave's 8 index pairs loaded once
__global__ __launch_bounds__(256) void k_decode(const int* __restrict__ ia,
                                                const int* __restrict__ ib,
                                                const _Float16* __restrict__ z,
                                                float* __restrict__ out, int M) {
  const int lane = threadIdx.x & 63;
  const int sub = lane & 7;
  const int eo = lane >> 3;                      // edge slot within wave (0..7)
  int base = (blockIdx.x * 256 + (threadIdx.x & ~63)) >> 3;  // wave's first edge
  int a8 = 0, b8 = 0;
  if (lane < 8 && base + lane < M) {
    a8 = ia[base + lane];
    b8 = ib[base + lane];
  }
  int e = base + eo;
  if (e >= M) return;
  int a = __shfl(a8, eo, 64);
  int b = __shfl(b8, eo, 64);
  half8 va = ((const half8*)z)[(size_t)a * 8 + sub];
  half8 vb = ((const half8*)z)[(size_t)b * 8 + sub];
  float v = 0.f;
#pragma unroll
  for (int i = 0; i < 8; ++i) v += (float)va[i] * (float)vb[i];
  v += __shfl_xor(v, 4, 64);
  v += __shfl_xor(v, 2, 64);
  v += __shfl_xor(v, 1, 64);
  if (sub == 0) out[e] = v;
}

extern "C" void kernel_launch(void* const* d_in, const int* in_sizes, int n_in,
                              void* d_out, int out_size, void* d_ws, size_t ws_size,
                              hipStream_t stream) {
  const float* x   = (const float*)d_in[0];
  const int*   ei  = (const int*)d_in[1];
  const int*   eli = (const int*)d_in[2];
  const float* W1  = (const float*)d_in[3];
  const float* b1  = (const float*)d_in[4];
  const float* W2  = (const float*)d_in[5];
  const float* b2  = (const float*)d_in[6];
  float* outp = (float*)d_out;

  const int E = in_sizes[1] / 2;   // 800000
  const int M = in_sizes[2] / 2;   // 200000
  const int* src = ei;
  const int* dst = ei + E;
  const int* la  = eli;
  const int* lb  = eli + M;

  float* ws      = (float*)d_ws;
  float* dinv    = ws;
  int*   rowptr  = (int*)(ws + OFF_ROWPTR);
  uint*  desc    = (uint*)(ws + OFF_DESC);
  int*   cnt     = (int*)(ws + OFF_CNT);
  int*   esrc    = (int*)(ws + OFF_ESRC);
  uint*  epos    = (uint*)(ws + OFF_EPOS);
  _Float16* W1t  = (_Float16*)(ws + OFF_W1T);
  _Float16* W2t  = (_Float16*)(ws + OFF_W2T);
  ushort* h1b    = (ushort*)(ws + OFF_H1B);
  ushort* h2b    = (ushort*)(ws + OFF_H1B);   // reuse (h1b dead after pull1)
  _Float16* out1h = (_Float16*)(ws + OFF_OUT1);
  _Float16* z    = (_Float16*)(ws + OFF_Z);

  // CSR build + degree norm + weight prep
  k_zero_prep<<<NB + 96, 256, 0, stream>>>(cnt, desc, W1, W2, W1t, W2t);
  k_hist  <<<FILLB, 256, 0, stream>>>(dst, E, cnt, epos);
  k_scanlb<<<NB, 256, 0, stream>>>(cnt, rowptr, dinv, desc, E);

  // fill + layer-1 GEMM fused (independent given scanlb)
  k_fill_gemm1<<<FILLB + (N_NODES + 63) / 64, 256, 0, stream>>>(
      src, epos, E, rowptr, esrc, x, W1t, dinv, h1b);
  k_pull1<<<12500, 256, 0, stream>>>(rowptr, esrc, dinv, (const uint*)h1b, b1,
                                     (uint*)out1h);

  // layer 2
  k_gemm2<<<(N_NODES + 63) / 64, 256, 0, stream>>>(out1h, W2t, dinv, h2b);
  k_pull2<<<12500, 256, 0, stream>>>(rowptr, esrc, dinv, h2b, b2, z);

  // decode
  k_decode<<<6250, 256, 0, stream>>>(la, lb, z, outp, M);
}